// Round 22
// baseline (700.198 us; speedup 1.0000x reference)
//
#include <hip/hip_runtime.h>

#define B 128
#define C 32
#define HH 16
#define V 4096
#define MARGIN 1e-4f

typedef __attribute__((ext_vector_type(8))) short bf16x8;
typedef __attribute__((ext_vector_type(4))) float f32x4;

// ---------------- helpers ----------------

__device__ __forceinline__ float cubicw(float t) {
    float at = fabsf(t);
    float at2 = at * at, at3 = at2 * at;
    if (at <= 1.f) return 1.25f * at3 - 2.25f * at2 + 1.f;
    if (at < 2.f)  return -0.75f * at3 + 3.75f * at2 - 6.f * at + 3.f;
    return 0.f;
}

__device__ __forceinline__ unsigned short f2bf_rne(float f) {
    unsigned int u = __float_as_uint(f);
    unsigned int r = (u + 0x7fffu + ((u >> 16) & 1u)) >> 16;
    return (unsigned short)r;
}
__device__ __forceinline__ float bf2f(unsigned short h) {
    return __uint_as_float(((unsigned int)h) << 16);
}

// ---------------- kernels ----------------

// setup: f_rest=feat, f_hat=0, c2 (fp64+fp32), stage-0 z, codebook bf16 hi/lo frag tables
__global__ void setup_kernel(const float* __restrict__ feat, float* __restrict__ f_rest,
                             float* __restrict__ f_hat, const float* __restrict__ cb,
                             double* __restrict__ c2d, float* __restrict__ c2f,
                             float* __restrict__ z0, unsigned short* __restrict__ cbh,
                             unsigned short* __restrict__ cbl) {
    int i = blockIdx.x * 256 + threadIdx.x;
    if (i < B * C * HH * HH) { f_rest[i] = feat[i]; f_hat[i] = 0.f; }
    if (i < V) {
        const float* p = cb + i * C;
        double s = 0.0;
        #pragma unroll
        for (int j = 0; j < C; ++j) { double d = (double)p[j]; s = fma(d, d, s); }
        c2d[i] = s;
        c2f[i] = (float)s;
    }
    if (i < B * C) {
        const float* p = feat + i * (HH * HH);
        float s = 0.f;
        for (int px = 0; px < HH * HH; ++px) s += p[px];
        z0[i] = s * (1.f / 256.f);
    }
    if (i < V * C) {
        int ii = i & 7, nn = (i >> 3) & 15, kb = (i >> 7) & 3, T = i >> 9;
        float val = cb[(T * 16 + nn) * C + kb * 8 + ii];
        unsigned short h = f2bf_rne(val);
        cbh[i] = h;
        cbl[i] = f2bf_rne(val - bf2f(h));
    }
}

// ---- MFMA top-2 scan v6: 16 tokens/wave (fits 44-VGPR envelope, R21) + 2-tile
// ILP: both tiles' loads issued before the MFMA block so L2 latency overlaps. ----
__global__ __launch_bounds__(256) void scan_mfma_kernel(
    const float* __restrict__ z, const unsigned short* __restrict__ cbh,
    const unsigned short* __restrict__ cbl, const float* __restrict__ c2f,
    float4* __restrict__ pk, int npx, int nseg, int ngrp)
{
    int tid = threadIdx.x;
    int wave = tid >> 6, lane = tid & 63;
    int job = blockIdx.x * 4 + wave;
    int seg = job / ngrp, tokgrp = job - seg * ngrp;
    int cps = V / nseg;
    int total = B * npx;
    int tn = lane & 15, kb = lane >> 4;

    __shared__ float smb1[4][16 * 17];
    __shared__ float smb2[4][16 * 17];
    __shared__ int   smi1[4][16 * 17];

    bf16x8 ah, al;
    {
        int tok = tokgrp * 16 + tn;
        int bq = tok / npx, n = tok - bq * npx;
        #pragma unroll
        for (int i = 0; i < 8; ++i) {
            float v = z[(bq * C + kb * 8 + i) * npx + n];
            unsigned short h = f2bf_rne(v);
            ah[i] = (short)h;
            al[i] = (short)f2bf_rne(v - bf2f(h));
        }
    }

    const bf16x8* ph = reinterpret_cast<const bf16x8*>(cbh);
    const bf16x8* pl = reinterpret_cast<const bf16x8*>(cbl);

    float b1[4], b2[4]; int i1[4];
    #pragma unroll
    for (int s = 0; s < 4; ++s) { b1[s] = 3e38f; b2[s] = 3e38f; i1[s] = 0; }

    int T0 = seg * (cps >> 4), nT = cps >> 4;   // nT even at every stage
    #pragma unroll 1
    for (int t = 0; t < nT; t += 2) {
        int T = T0 + t;
        bf16x8 bh0 = ph[(size_t)T * 64 + lane];
        bf16x8 bl0 = pl[(size_t)T * 64 + lane];
        bf16x8 bh1 = ph[(size_t)(T + 1) * 64 + lane];
        bf16x8 bl1 = pl[(size_t)(T + 1) * 64 + lane];
        float c20 = c2f[T * 16 + tn];
        float c21 = c2f[(T + 1) * 16 + tn];

        f32x4 a0 = {0.f, 0.f, 0.f, 0.f}, a1 = {0.f, 0.f, 0.f, 0.f};
        a0 = __builtin_amdgcn_mfma_f32_16x16x32_bf16(ah, bh0, a0, 0, 0, 0);
        a0 = __builtin_amdgcn_mfma_f32_16x16x32_bf16(al, bh0, a0, 0, 0, 0);
        a0 = __builtin_amdgcn_mfma_f32_16x16x32_bf16(ah, bl0, a0, 0, 0, 0);
        a0 = __builtin_amdgcn_mfma_f32_16x16x32_bf16(al, bl0, a0, 0, 0, 0);
        a1 = __builtin_amdgcn_mfma_f32_16x16x32_bf16(ah, bh1, a1, 0, 0, 0);
        a1 = __builtin_amdgcn_mfma_f32_16x16x32_bf16(al, bh1, a1, 0, 0, 0);
        a1 = __builtin_amdgcn_mfma_f32_16x16x32_bf16(ah, bl1, a1, 0, 0, 0);
        a1 = __builtin_amdgcn_mfma_f32_16x16x32_bf16(al, bl1, a1, 0, 0, 0);

        int code0 = T * 16 + tn;          // tile t first, then t+1: ascending codes
        int code1 = code0 + 16;
        #pragma unroll
        for (int r = 0; r < 4; ++r) {
            float s0 = fmaf(-2.f, a0[r], c20);
            if (s0 < b1[r]) { b2[r] = b1[r]; b1[r] = s0; i1[r] = code0; }
            else if (s0 < b2[r]) { b2[r] = s0; }
            float s1 = fmaf(-2.f, a1[r], c21);
            if (s1 < b1[r]) { b2[r] = b1[r]; b1[r] = s1; i1[r] = code1; }
            else if (s1 < b2[r]) { b2[r] = s1; }
        }
    }

    #pragma unroll
    for (int r = 0; r < 4; ++r) {
        int tokl = kb * 4 + r;
        smb1[wave][tokl * 17 + tn] = b1[r];
        smb2[wave][tokl * 17 + tn] = b2[r];
        smi1[wave][tokl * 17 + tn] = i1[r];
    }
    __syncthreads();
    if (tid < 64) {
        int w = tid >> 4, tl = tid & 15;
        int jobw = blockIdx.x * 4 + w;
        int segw = jobw / ngrp, tgw = jobw - segw * ngrp;
        float gb1 = 3e38f, gb2 = 3e38f; int gi1 = 0;
        #pragma unroll
        for (int i = 0; i < 16; ++i) {
            float v1 = smb1[w][tl * 17 + i];
            int   ix = smi1[w][tl * 17 + i];
            if (v1 < gb1 || (v1 == gb1 && ix < gi1)) { gb2 = gb1; gb1 = v1; gi1 = ix; }
            else if (v1 < gb2) { gb2 = v1; }
            float v2 = smb2[w][tl * 17 + i];
            if (v2 < gb2) gb2 = v2;
        }
        int tok = tgw * 16 + tl;
        float4 o;
        o.x = gb1; o.y = gb2; o.z = __int_as_float(gi1); o.w = 0.f;
        pk[(size_t)segw * total + tok] = o;
    }
}

// fused tail v5: B*8 blocks (4 out-ch each), LDS < 40 KB -> 4 blocks/CU residency
// (R21: 512-block grid capped overlap at 2/CU). Recheck scratch overlaid into Bc.
__global__ __launch_bounds__(256) void stage_tail_kernel(
    const float4* __restrict__ pk, const float* __restrict__ z,
    const float* __restrict__ cb, const double* __restrict__ c2d,
    const float* __restrict__ w, const float* __restrict__ bias,
    float* __restrict__ f_hat, float* __restrict__ f_rest,
    float* __restrict__ out, float* __restrict__ znext,
    int pn, int off, int pn2, int nseg)
{
    int bb = blockIdx.x >> 3;
    int og = (blockIdx.x & 7) * 4;
    int tid = threadIdx.x;
    int npx = pn * pn;
    int total = B * npx;

    __shared__ float A_s[32][257];            // gather -> hu -> fh/fr overlay (rows 0..7)
    __shared__ alignas(16) float Bc[4][260];  // bicubic v-pass temp; recheck overlay
    __shared__ int idx_s[256];
    __shared__ int flist[256];
    __shared__ int fcnt;
    __shared__ float wtab[16][4];
    __shared__ int   itab[16][4];
    float (*fh_s)[257] = &A_s[0];
    float (*fr_s)[257] = &A_s[4];
    // recheck scratch overlays Bc (disjoint in time: recheck ends before bicubic)
    double* zsd  = (double*)&Bc[0][0];        // 256 B
    double* sred = (double*)((char*)&Bc[0][0] + 256);   // 2 KB
    int*    sidx = (int*)((char*)&Bc[0][0] + 2304);     // 1 KB  (total 3.3 KB <= 4.1 KB)

    float pf[4], pr[4];
    #pragma unroll
    for (int o = 0; o < 4; ++o) {
        int gi = (bb * 32 + og + o) * 256 + tid;
        pf[o] = f_hat[gi]; pr[o] = f_rest[gi];
    }

    if (tid < 16) {
        float scale = (float)pn * (1.f / 16.f);
        float src = (tid + 0.5f) * scale - 0.5f;
        int fi = (int)floorf(src);
        float t = src - (float)fi;
        #pragma unroll
        for (int k = 0; k < 4; ++k) {
            wtab[tid][k] = cubicw((float)(k - 1) - t);
            itab[tid][k] = min(max(fi + k - 1, 0), pn - 1);
        }
    }
    if (tid == 0) fcnt = 0;
    __syncthreads();

    // combine per-segment top-2 (one 16B load per segment)
    if (tid < npx) {
        int tok = bb * npx + tid;
        float gb1 = 3e38f, gb2 = 3e38f; int gi1 = 0;
        for (int s = 0; s < nseg; ++s) {
            float4 e = pk[(size_t)s * total + tok];
            float v1 = e.x; int ix = __float_as_int(e.z);
            if (v1 < gb1 || (v1 == gb1 && ix < gi1)) { gb2 = gb1; gb1 = v1; gi1 = ix; }
            else if (v1 < gb2) { gb2 = v1; }
            if (e.y < gb2) gb2 = e.y;
        }
        idx_s[tid] = gi1;
        if (gb2 - gb1 < MARGIN) { int slot = atomicAdd(&fcnt, 1); flist[slot] = tid; }
    }
    __syncthreads();

    // exact fp64 rescan for ambiguous tokens (rare)
    int nf = fcnt;
    for (int f = 0; f < nf; ++f) {
        int n = flist[f];
        if (tid < C) zsd[tid] = (double)z[(bb * C + tid) * npx + n];
        __syncthreads();
        double best = 1e300; int bi = 0x7fffffff;
        for (int k = 0; k < V / 256; ++k) {
            int v = tid + k * 256;
            const float4* cp = reinterpret_cast<const float4*>(cb + (size_t)v * C);
            double acc = 0.0;
            #pragma unroll
            for (int qq = 0; qq < 8; ++qq) {
                float4 fv = cp[qq];
                acc = fma((double)fv.x, zsd[4 * qq + 0], acc);
                acc = fma((double)fv.y, zsd[4 * qq + 1], acc);
                acc = fma((double)fv.z, zsd[4 * qq + 2], acc);
                acc = fma((double)fv.w, zsd[4 * qq + 3], acc);
            }
            double s = fma(-2.0, acc, c2d[v]);
            if (s < best || (s == best && v < bi)) { best = s; bi = v; }
        }
        sred[tid] = best; sidx[tid] = bi;
        __syncthreads();
        for (int st = 128; st > 0; st >>= 1) {
            if (tid < st) {
                double o = sred[tid + st]; int oi = sidx[tid + st];
                double me = sred[tid];     int mi = sidx[tid];
                if (o < me || (o == me && oi < mi)) { sred[tid] = o; sidx[tid] = oi; }
            }
            __syncthreads();
        }
        if (tid == 0) idx_s[n] = sidx[0];
        __syncthreads();
    }
    __syncthreads();

    // gather all 32 channels
    for (int e = tid; e < 32 * npx; e += 256) {
        int c = e & 31, n = e >> 5;
        A_s[c][n] = cb[idx_s[n] * 32 + c];
    }
    __syncthreads();

    // separable bicubic in 8 chunks of 4 channels (Bc = v-pass temp)
    #pragma unroll 1
    for (int ch = 0; ch < 8; ++ch) {
        for (int e = tid; e < 4 * 16 * pn; e += 256) {
            int wx = e % pn; int rest = e / pn;
            int p = rest & 15, cl = rest >> 4;
            float s = 0.f;
            #pragma unroll
            for (int k = 0; k < 4; ++k)
                s = fmaf(wtab[p][k], A_s[ch * 4 + cl][itab[p][k] * pn + wx], s);
            Bc[cl][p * pn + wx] = s;
        }
        __syncthreads();
        #pragma unroll
        for (int it = 0; it < 4; ++it) {
            int e = tid + it * 256;
            int q = e & 15, p = (e >> 4) & 15, cl = e >> 8;
            float s = 0.f;
            #pragma unroll
            for (int k = 0; k < 4; ++k)
                s = fmaf(wtab[q][k], Bc[cl][p * pn + itab[q][k]], s);
            A_s[ch * 4 + cl][e & 255] = s;
        }
        __syncthreads();
    }

    // conv 3x3 SAME over 32 in-ch (A_s = hu) for out-ch og..og+3 (w wave-uniform -> s_load)
    int p = tid >> 4, q = tid & 15;
    float acc[4];
    #pragma unroll
    for (int o = 0; o < 4; ++o) acc[o] = bias[og + o];
    for (int i = 0; i < 32; ++i) {
        float v[9];
        #pragma unroll
        for (int dy = 0; dy < 3; ++dy)
            #pragma unroll
            for (int dx = 0; dx < 3; ++dx) {
                int pp = p + dy - 1, qq = q + dx - 1;
                bool in = (pp >= 0) & (pp < 16) & (qq >= 0) & (qq < 16);
                v[dy * 3 + dx] = in ? A_s[i][pp * 16 + qq] : 0.f;
            }
        #pragma unroll
        for (int o = 0; o < 4; ++o) {
            const float* wp_ = w + ((og + o) * 32 + i) * 9;
            #pragma unroll
            for (int k = 0; k < 9; ++k) acc[o] = fmaf(wp_[k], v[k], acc[o]);
        }
    }
    float hv[4];
    #pragma unroll
    for (int o = 0; o < 4; ++o) hv[o] = A_s[og + o][tid];
    __syncthreads();   // all A_s reads done before overlay writes

    #pragma unroll
    for (int o = 0; o < 4; ++o) {
        int gi = (bb * 32 + og + o) * 256 + tid;
        float blend = 0.5f * hv[o] + 0.5f * acc[o];
        float nf2 = pf[o] + blend;
        float nr2 = pr[o] - blend;
        f_hat[gi] = nf2; f_rest[gi] = nr2;
        fh_s[o][tid] = nf2; fr_s[o][tid] = nr2;
    }
    __syncthreads();

    // context pool (4 ch)
    for (int e = tid; e < 4 * npx; e += 256) {
        int o = e & 3, n = e >> 2;
        int y = n / pn, x = n - y * pn;
        int sh = (y * HH) / pn, eh = ((y + 1) * HH + pn - 1) / pn;
        int sw = (x * HH) / pn, ew = ((x + 1) * HH + pn - 1) / pn;
        float s = 0.f;
        for (int yy = sh; yy < eh; ++yy)
            for (int xx = sw; xx < ew; ++xx) s += fh_s[o][yy * 16 + xx];
        out[((bb * 680) + off + n) * 32 + og + o] = s * (1.f / (float)((eh - sh) * (ew - sw)));
    }

    // next-z pool (4 ch)
    if (pn2 > 0) {
        int npx2 = pn2 * pn2;
        for (int e = tid; e < 4 * npx2; e += 256) {
            int o = e / npx2, n = e - o * npx2;
            int y = n / pn2, x = n - y * pn2;
            int sh = (y * HH) / pn2, eh = ((y + 1) * HH + pn2 - 1) / pn2;
            int sw = (x * HH) / pn2, ew = ((x + 1) * HH + pn2 - 1) / pn2;
            float s = 0.f;
            for (int yy = sh; yy < eh; ++yy)
                for (int xx = sw; xx < ew; ++xx) s += fr_s[o][yy * 16 + xx];
            znext[(bb * 32 + og + o) * npx2 + n] = s * (1.f / (float)((eh - sh) * (ew - sw)));
        }
    }
}

// ---------------- launch ----------------

extern "C" void kernel_launch(void* const* d_in, const int* in_sizes, int n_in,
                              void* d_out, int out_size, void* d_ws, size_t ws_size,
                              hipStream_t stream) {
    const float* feat = (const float*)d_in[0];
    const float* cb   = (const float*)d_in[1];
    const float* phiw = (const float*)d_in[2];
    const float* phib = (const float*)d_in[3];
    float* out = (float*)d_out;
    float* wsf = (float*)d_ws;

    const int NE = B * C * HH * HH; // 1048576
    float* f_rest = wsf;
    float* f_hat  = wsf + NE;
    float* zA     = wsf + 2 * NE;
    float* zB     = wsf + 3 * NE;
    char*  tl     = (char*)(wsf + 4 * NE);
    double* c2d  = (double*)tl;                             // 32 KB
    float*  c2f  = (float*)(tl + (32 << 10));               // 16 KB
    float4* pk   = (float4*)(tl + (48 << 10));              // 4 MB
    unsigned short* cbh = (unsigned short*)(tl + (48 << 10) + (4 << 20));   // 256 KB
    unsigned short* cbl = (unsigned short*)(tl + (48 << 10) + (4 << 20) + (512 << 10));

    static const int PN_[10]   = {1, 2, 3, 4, 5, 6, 8, 10, 13, 16};
    static const int PI_[10]   = {0, 0, 1, 1, 1, 2, 2, 2, 3, 3};
    static const int OFF_[10]  = {0, 1, 5, 14, 30, 55, 91, 155, 255, 424};
    static const int NSEG_[10] = {32, 32, 32, 16, 16, 16, 8, 8, 8, 8};

    setup_kernel<<<dim3((NE + 255) / 256), dim3(256), 0, stream>>>(
        feat, f_rest, f_hat, cb, c2d, c2f, zA, cbh, cbl);

    for (int si = 0; si < 10; ++si) {
        int pn = PN_[si], npx = pn * pn;
        int tokens = B * npx;
        int nseg = NSEG_[si];
        int ngrp = tokens / 16;
        int njobs = ngrp * nseg;         // divisible by 4 at every stage
        float* zin  = (si & 1) ? zB : zA;
        float* zout = (si & 1) ? zA : zB;

        scan_mfma_kernel<<<dim3(njobs / 4), dim3(256), 0, stream>>>(
            zin, cbh, cbl, c2f, pk, npx, nseg, ngrp);

        int pn2 = (si < 9) ? PN_[si + 1] : 0;
        stage_tail_kernel<<<dim3(B * 8), dim3(256), 0, stream>>>(
            pk, zin, cb, c2d,
            phiw + PI_[si] * C * C * 9, phib + PI_[si] * C,
            f_hat, f_rest, out, zout, pn, OFF_[si], pn2, nseg);
    }
}